// Round 9
// baseline (428.790 us; speedup 1.0000x reference)
//
#include <hip/hip_runtime.h>
#include <hip/hip_bf16.h>
#include <stdint.h>

#define BATCH 128
#define SEQ   512
#define NW    6
#define DIM   64
#define NELEM (BATCH * SEQ * NW)   // 393216
#define PI_F  3.14159265358979323846f
#define MSTRIDE 132                // padded row stride (words); 528B, 16B-aligned

typedef float v2f __attribute__((ext_vector_type(2)));

// ---------------------------------------------------------------------------
// Interleaved 6-way DPP wave-64 reduction (VALU pipe). Totals land in lane 63.
// ---------------------------------------------------------------------------
template <int CTRL>
__device__ __forceinline__ void red_stage6(float v[6]) {
#pragma unroll
    for (int w = 0; w < 6; ++w)
        v[w] += __int_as_float(__builtin_amdgcn_update_dpp(
            0, __float_as_int(v[w]), CTRL, 0xF, 0xF, false));
}

// Branch-free sincos(h/2) for |h| <= 1 (h is a bounded expectation value).
__device__ __forceinline__ void sincos_half(float h, float& s, float& c) {
    const float u = h * h;
    c = fmaf(u, fmaf(u, fmaf(u, -2.1701389e-5f, 2.6041667e-3f), -0.125f), 1.0f);
    s = h * fmaf(u, fmaf(u, fmaf(u, -1.5501e-6f, 2.6041667e-4f), -2.0833333e-2f), 0.5f);
}

// ---------------------------------------------------------------------------
// Kernel 1: bf16-vs-f32 detection on `angles` (U(0,pi) data).
// ---------------------------------------------------------------------------
__global__ void k_detect(const uint32_t* __restrict__ a, int* __restrict__ flag) {
    __shared__ int cnt;
    if (threadIdx.x == 0) cnt = 0;
    __syncthreads();
    uint32_t w = a[threadIdx.x];
    uint32_t e = (w >> 8) & 0xFFu;
    if (e >= 0x3Au && e <= 0x41u) atomicAdd(&cnt, 1);
    __syncthreads();
    if (threadIdx.x == 0) *flag = (cnt >= 128) ? 1 : 0;   // 1 = bf16
}

__device__ __forceinline__ float ldf(const void* p, int i, bool bf) {
    if (bf) {
        uint32_t u = (uint32_t)((const uint16_t*)p)[i];
        return __uint_as_float(u << 16);
    }
    return ((const float*)p)[i];
}

// ---------------------------------------------------------------------------
// Kernel 2: inputs -> f32 ws; precompute cos(x), sin(x) (full angle).
// cs layout: [b][t][w][2]. misc: [0..3]=poly, [4..39]=fwd, [40..75]=bwd,
// [76]=fc, [77]=bc.
// ---------------------------------------------------------------------------
__global__ void k_convert(const void* ang, const void* poly, const void* fp,
                          const void* bp, const void* fc, const void* bc,
                          float* __restrict__ cs, float* __restrict__ misc,
                          const int* __restrict__ flag) {
    const bool bf = (*flag != 0);
    const int i = blockIdx.x * blockDim.x + threadIdx.x;
    if (i < NELEM) {
        float x = ldf(ang, i, bf);
        float s, c;
        __sincosf(x, &s, &c);
        cs[2 * i]     = c;
        cs[2 * i + 1] = s;
    }
    if (i < 4)                    misc[i]            = ldf(poly, i, bf);
    else if (i >= 64 && i < 100)  misc[4 + (i - 64)] = ldf(fp, i - 64, bf);
    else if (i >= 128 && i < 164) misc[40 + (i - 128)] = ldf(bp, i - 128, bf);
    else if (i == 200)            misc[76] = ldf(fc, 0, bf);
    else if (i == 201)            misc[77] = ldf(bc, 0, bf);
}

// ---------------------------------------------------------------------------
// Kernel 3: precompute M[dir] (full step unitary minus encode/injection) as
// an explicit 64x64 complex matrix by evolving basis columns.
// Mg layout: [dir][row][col][2] floats. Runs once; perf-irrelevant.
// ---------------------------------------------------------------------------
__global__ void __launch_bounds__(64) k_msetup(const float* __restrict__ misc,
                                               float* __restrict__ Mg) {
    const int p   = threadIdx.x;
    const int col = blockIdx.x & 63;
    const int dir = blockIdx.x >> 6;
    const float* poly = misc;
    const float* prm  = misc + (dir ? 40 : 4);

    float yr = (p == col) ? 1.f : 0.f;
    float yi = 0.f;

#pragma unroll
    for (int d = 0; d < 4; ++d) {
        const float th = 0.5f * PI_F * poly[d] *
                         (float)(6 - 2 * (int)__popc((unsigned)p));
        float s, c;
        __sincosf(th, &s, &c);
        const float nr = yr * c + yi * s;
        const float ni = yi * c - yr * s;
        yr = nr; yi = ni;
#pragma unroll
        for (int k = 0; k < 6; ++k) {
            const int cw = k, tw = (k + 1) % 6;
            const int src = p ^ (((p >> (5 - cw)) & 1) << (5 - tw));
            yr = __shfl(yr, src, 64);
            yi = __shfl(yi, src, 64);
        }
    }

    int idx = 0;
#pragma unroll
    for (int l = 0; l < 2; ++l) {
#pragma unroll
        for (int w = 0; w < 6; ++w) {
            float cx, sx, cy, sy, cz, sz;
            __sincosf(0.5f * prm[idx + 0], &sx, &cx);
            __sincosf(0.5f * prm[idx + 1], &sy, &cy);
            __sincosf(0.5f * prm[idx + 2], &sz, &cz);
            idx += 3;
            const float A = cy * cx, B = sy * sx, C = sy * cx, D = cy * sx;
            const float U00r = cz * A + sz * B, U00i = cz * B - sz * A;
            const float U11r = U00r,            U11i = sz * A - cz * B;
            const float Xr   = cz * C + sz * D, Xi   = sz * C - cz * D;
            const int m  = 1 << (5 - w);
            const int bb = (p >> (5 - w)) & 1;
            const float C1r = bb ? U11r : U00r;
            const float C1i = bb ? U11i : U00i;
            const float C2r = bb ? Xr : -Xr;
            const float C2i = Xi;
            const float pr = __shfl_xor(yr, m, 64);
            const float pi = __shfl_xor(yi, m, 64);
            const float nr = C1r * yr - C1i * yi + C2r * pr - C2i * pi;
            const float ni = C1r * yi + C1i * yr + C2r * pi + C2i * pr;
            yr = nr; yi = ni;
        }
#pragma unroll
        for (int k = 0; k < 5; ++k) {
            const int src = p ^ (((p >> (5 - k)) & 1) << (5 - (k + 1)));
            yr = __shfl(yr, src, 64);
            yi = __shfl(yi, src, 64);
        }
    }

    float* out = Mg + ((size_t)(dir * 64 + p) * 64 + (size_t)col) * 2;
    out[0] = yr;
    out[1] = yi;
}

// ---------------------------------------------------------------------------
// Kernel 4: recurrent sim. ONE WAVE per chain (1 block/CU), M staged in LDS.
// vs r8: no barriers, no cross-wave exchange, no redundant compute.
//  - Lane p owns row p of M, read per step as 32 ds_read_b128 from a padded
//    (132-word stride) LDS image — overlaps the pk_fma issue.
//  - x never materializes: each lane computes the full tensor factors
//    G[8] (wires 0-2), L[8] (wires 3-5); matvec nests as
//    y = sum_a G[a] * (sum_b L[b] * Mrow[8a+b])  — 72 packed v2f FMAs.
//  - cs cos/sin read from global with cross-step prefetch (no barrier = no
//    forced vmcnt drain). Outputs buffered in LDS, bulk-stored at the end.
// ---------------------------------------------------------------------------
__global__ void __launch_bounds__(64, 1) k_sim(const float* __restrict__ cs,
                                               const float* __restrict__ Mg,
                                               float* __restrict__ hbuf) {
    const int lane  = threadIdx.x;
    const int chain = blockIdx.x;            // 0..255
    const int dir   = chain >> 7;
    const int b     = chain & 127;
    float* orow = hbuf + (size_t)dir * NELEM + (size_t)b * (SEQ * NW);
    const float* csrow = cs + (size_t)b * (SEQ * NW * 2);

    __shared__ float Ml[DIM * MSTRIDE];      // 33 KB padded M image
    __shared__ float zb[SEQ * NW];           // 12 KB output buffer

    // ---- stage my row of M into LDS (once) ----
    {
        const float4* mrow = (const float4*)(Mg + (size_t)(dir * 64 + lane) * 128);
        float4* dst = (float4*)(Ml + lane * MSTRIDE);
#pragma unroll
        for (int cc = 0; cc < 32; ++cc) dst[cc] = mrow[cc];
    }
    __syncthreads();                         // one-time; orders stage vs reads

    int zmask[6];
#pragma unroll
    for (int w = 0; w < 6; ++w) zmask[w] = ((lane >> (5 - w)) & 1) << 31;

    float h[6] = {0.f, 0.f, 0.f, 0.f, 0.f, 0.f};

    const int tin0 = dir ? SEQ - 1 : 0;
    const float4* x0p = (const float4*)(csrow + tin0 * 12);
    float4 xq0 = x0p[0], xq1 = x0p[1], xq2 = x0p[2];

    const float4* Mrow4 = (const float4*)(Ml + lane * MSTRIDE);

    for (int t = 0; t < SEQ; ++t) {
        const int tin  = dir ? (SEQ - 1 - t) : t;
        const int tn   = (t + 1 < SEQ) ? t + 1 : t;
        const int tinn = dir ? (SEQ - 1 - tn) : tn;
        const float4* xnp = (const float4*)(csrow + tinn * 12);
        float4 nx0 = xnp[0], nx1 = xnp[1], nx2 = xnp[2];   // prefetch t+1

        // ---- encode: tensor factors (wave-uniform, per-lane registers) ----
        float cw6[6], sw6[6];
#pragma unroll
        for (int w = 0; w < 6; ++w) sincos_half(h[w], sw6[w], cw6[w]);
        float G[8], L[8];
        {
            const float g00 = cw6[0] * cw6[1], g01 = cw6[0] * sw6[1];
            const float g10 = sw6[0] * cw6[1], g11 = sw6[0] * sw6[1];
            G[0] = g00 * cw6[2]; G[1] = g00 * sw6[2];
            G[2] = g01 * cw6[2]; G[3] = g01 * sw6[2];
            G[4] = g10 * cw6[2]; G[5] = g10 * sw6[2];
            G[6] = g11 * cw6[2]; G[7] = g11 * sw6[2];
            const float l00 = cw6[3] * cw6[4], l01 = cw6[3] * sw6[4];
            const float l10 = sw6[3] * cw6[4], l11 = sw6[3] * sw6[4];
            L[0] = l00 * cw6[5]; L[1] = l00 * sw6[5];
            L[2] = l01 * cw6[5]; L[3] = l01 * sw6[5];
            L[4] = l10 * cw6[5]; L[5] = l10 * sw6[5];
            L[6] = l11 * cw6[5]; L[7] = l11 * sw6[5];
        }

        // ---- matvec: y = sum_a G[a] * (sum_b L[b] * Mrow[8a+b]) ----
        v2f y = {0.f, 0.f};
#pragma unroll
        for (int a = 0; a < 8; ++a) {
            const float4 c0 = Mrow4[4 * a + 0];
            const float4 c1 = Mrow4[4 * a + 1];
            const float4 c2 = Mrow4[4 * a + 2];
            const float4 c3 = Mrow4[4 * a + 3];
            v2f T = {0.f, 0.f};
            T += L[0] * (v2f){c0.x, c0.y};
            T += L[1] * (v2f){c0.z, c0.w};
            T += L[2] * (v2f){c1.x, c1.y};
            T += L[3] * (v2f){c1.z, c1.w};
            T += L[4] * (v2f){c2.x, c2.y};
            T += L[5] * (v2f){c2.z, c2.w};
            T += L[6] * (v2f){c3.x, c3.y};
            T += L[7] * (v2f){c3.z, c3.w};
            y += G[a] * T;
        }
        const float yr = y.x, yi = y.y;

        // ---- measurement: batched partner shuffles, then fold injection ----
        float pr[6], pi[6];
#pragma unroll
        for (int w = 0; w < 6; ++w) pr[w] = __shfl_xor(yr, 1 << (5 - w), 64);
#pragma unroll
        for (int w = 0; w < 6; ++w) pi[w] = __shfl_xor(yi, 1 << (5 - w), 64);

        const float q = yr * yr + yi * yi;
        float cxw[6], sxw[6];
        cxw[0] = xq0.x; sxw[0] = xq0.y; cxw[1] = xq0.z; sxw[1] = xq0.w;
        cxw[2] = xq1.x; sxw[2] = xq1.y; cxw[3] = xq1.z; sxw[3] = xq1.w;
        cxw[4] = xq2.x; sxw[4] = xq2.y; cxw[5] = xq2.z; sxw[5] = xq2.w;

        float v[6];
#pragma unroll
        for (int w = 0; w < 6; ++w) {
            const float ac = yr * pr[w] + yi * pi[w];
            const float sq = __int_as_float(__float_as_int(q) ^ zmask[w]);
            v[w] = cxw[w] * sq - sxw[w] * ac;
        }

        // ---- interleaved 6-way DPP reduction; totals in lane 63 ----
        red_stage6<0x111>(v);   // row_shr:1
        red_stage6<0x112>(v);   // row_shr:2
        red_stage6<0x114>(v);   // row_shr:4
        red_stage6<0x118>(v);   // row_shr:8
        red_stage6<0x142>(v);   // row_bcast:15
        red_stage6<0x143>(v);   // row_bcast:31

        // lane 63 buffers this step's outputs directly from its totals
        if (lane == 63) {
#pragma unroll
            for (int w = 0; w < 6; ++w) zb[tin * NW + w] = v[w];
        }

        // uniform next-h via readlane
#pragma unroll
        for (int w = 0; w < 6; ++w)
            h[w] = __int_as_float(
                __builtin_amdgcn_readlane(__float_as_int(v[w]), 63));

        xq0 = nx0; xq1 = nx1; xq2 = nx2;
    }
    __syncthreads();                         // order zb writes vs bulk read

    // ---- bulk store outputs: 3072 floats = 768 float4 over 64 lanes ----
    {
        const float4* zs4 = (const float4*)zb;
        float4* go = (float4*)orow;
#pragma unroll
        for (int k = 0; k < 12; ++k) {
            const int idx = lane + k * 64;
            go[idx] = zs4[idx];
        }
    }
}

// ---------------------------------------------------------------------------
// Kernel 5: out = sigmoid(fc)*h_fwd + sigmoid(bc)*h_bwd, dtype per flag.
// ---------------------------------------------------------------------------
__global__ void k_combine(const float* __restrict__ hbuf,
                          const float* __restrict__ misc,
                          void* __restrict__ out, const int* __restrict__ flag) {
    const int i = blockIdx.x * blockDim.x + threadIdx.x;
    if (i >= NELEM) return;
    const float sf = 1.f / (1.f + __expf(-misc[76]));
    const float sb = 1.f / (1.f + __expf(-misc[77]));
    const float v = sf * hbuf[i] + sb * hbuf[NELEM + i];
    if (*flag) ((__hip_bfloat16*)out)[i] = __float2bfloat16(v);
    else       ((float*)out)[i] = v;
}

// ---------------------------------------------------------------------------
extern "C" void kernel_launch(void* const* d_in, const int* in_sizes, int n_in,
                              void* d_out, int out_size, void* d_ws, size_t ws_size,
                              hipStream_t stream) {
    const void* ang  = d_in[0];
    const void* poly = d_in[1];
    const void* fp   = d_in[2];
    const void* bp   = d_in[3];
    const void* fc   = d_in[4];
    const void* bc   = d_in[5];

    // ws (floats): cs[2*NELEM] | misc[128] | hbuf[2*NELEM] | M[16384] | flag
    float* cs   = (float*)d_ws;
    float* misc = cs + 2 * NELEM;
    float* hbuf = misc + 128;
    float* Mg   = hbuf + 2 * NELEM;
    int*   flag = (int*)(Mg + 2 * 64 * 64 * 2);

    k_detect<<<1, 256, 0, stream>>>((const uint32_t*)ang, flag);
    k_convert<<<(NELEM + 255) / 256, 256, 0, stream>>>(ang, poly, fp, bp, fc, bc,
                                                       cs, misc, flag);
    k_msetup<<<128, 64, 0, stream>>>(misc, Mg);
    k_sim<<<256, 64, 0, stream>>>(cs, Mg, hbuf);
    k_combine<<<(NELEM + 255) / 256, 256, 0, stream>>>(hbuf, misc, d_out, flag);
}